// Round 1
// baseline (284.133 us; speedup 1.0000x reference)
//
#include <hip/hip_runtime.h>

#define NPIX (512*512)
#define CSZ 13552   // padded coefficient table size (floats)

// ---------------------------------------------------------------------------
// Init kernel: build the 8 per-path coefficient tensors coef[p][i][j][k] =
// 0.5 * tp_w[p] * Cr[i][j][k]  (Cr = real-basis Wigner 3j * sqrt(2lc+1)),
// padded so each k-run is a multiple of 4 floats (12 for nc=9, 16 for nc=13).
// ---------------------------------------------------------------------------

static __device__ __forceinline__ int qcol(int l, int c, int* row, double* re, double* im) {
  const double S = 0.70710678118654752440;  // 1/sqrt(2)
  int p = c - l;
  if (p == 0) { row[0] = l; re[0] = 1.0; im[0] = 0.0; return 1; }
  if (p > 0) {
    row[0] = l - p; re[0] = S;                 im[0] = 0.0;
    row[1] = l + p; re[1] = (p & 1) ? -S : S;  im[1] = 0.0;
    return 2;
  }
  int a = -p;
  row[0] = l - a; re[0] = 0.0; im[0] = -S;
  row[1] = l + a; re[1] = 0.0; im[1] = (a & 1) ? -S : S;
  return 2;
}

__global__ void w3j_init(const float* __restrict__ tpw, float* __restrict__ coef) {
  __shared__ double sC[13*13*13];
  __shared__ double sfact[20];
  const int p = blockIdx.x;
  const int la = (p & 4) ? 6 : 4, lb = (p & 2) ? 6 : 4, lc = (p & 1) ? 6 : 4;
  const int na = 2*la+1, nb = 2*lb+1, nc = 2*lc+1, ncp = (nc + 3) & ~3;
  if (threadIdx.x == 0) {
    double f = 1.0; sfact[0] = 1.0;
    for (int i = 1; i < 20; ++i) { f *= (double)i; sfact[i] = f; }
  }
  int off = 0;
  for (int q = 0; q < p; ++q)
    off += ((q&4)?13:9) * ((q&2)?13:9) * ((q&1)?16:12);
  for (int e = threadIdx.x; e < na*nb*nc; e += blockDim.x) sC[e] = 0.0;
  __syncthreads();
  // SU(2) Clebsch-Gordan into sC[i][j][k3]
  for (int e = threadIdx.x; e < na*nb; e += blockDim.x) {
    int i = e / nb, j = e % nb;
    int m1 = i - la, m2 = j - lb, m3 = m1 + m2;
    if (m3 < -lc || m3 > lc) continue;
    double pre = sqrt((2.0*lc + 1.0) * sfact[lc+la-lb] * sfact[lc-la+lb] * sfact[la+lb-lc] / sfact[la+lb+lc+1]);
    pre *= sqrt(sfact[lc+m3]*sfact[lc-m3]*sfact[la-m1]*sfact[la+m1]*sfact[lb-m2]*sfact[lb+m2]);
    double s = 0.0;
    for (int k = 0; k <= la + lb - lc; ++k) {
      int d2 = la - m1 - k, d3 = lb + m2 - k, d4 = lc - lb + m1 + k, d5 = lc - la - m2 + k;
      if (d2 < 0 || d3 < 0 || d4 < 0 || d5 < 0) continue;
      s += ((k & 1) ? -1.0 : 1.0) /
           (sfact[k]*sfact[la+lb-lc-k]*sfact[d2]*sfact[d3]*sfact[d4]*sfact[d5]);
    }
    sC[(i*nb + j)*nc + (lc + m3)] = pre * s;
  }
  __syncthreads();
  // real-basis transform: Cr[a][b][c] = Re( (-i)^la (-i)^lb conj((-i)^lc) *
  //   sum Q1[i,a] Q2[k,b] conj(Q3[m,c]) C[i,k,m] ); phases are real for even l.
  const double PH = (((la/2)&1)?-1.0:1.0)*(((lb/2)&1)?-1.0:1.0)*(((lc/2)&1)?-1.0:1.0);
  const double scale = 0.5 * (double)tpw[p] * PH;
  for (int e = threadIdx.x; e < na*nb*ncp; e += blockDim.x) {
    int a = e / (nb*ncp), rem = e % (nb*ncp), b = rem / ncp, c = rem % ncp;
    float val = 0.0f;
    if (c < nc) {
      int r1[2]; double u1r[2], u1i[2]; int n1 = qcol(la, a, r1, u1r, u1i);
      int r2[2]; double u2r[2], u2i[2]; int n2 = qcol(lb, b, r2, u2r, u2i);
      int r3[2]; double u3r[2], u3i[2]; int n3 = qcol(lc, c, r3, u3r, u3i);
      double acc = 0.0;
      for (int u = 0; u < n1; ++u)
        for (int v = 0; v < n2; ++v) {
          double Rr = u1r[u]*u2r[v] - u1i[u]*u2i[v];
          double Ri = u1r[u]*u2i[v] + u1i[u]*u2r[v];
          for (int w = 0; w < n3; ++w) {
            double cv = sC[(r1[u]*nb + r2[v])*nc + r3[w]];
            // Re(z * conj(u3)) = Rr*u3r + Ri*u3i
            acc += (Rr*u3r[w] + Ri*u3i[w]) * cv;
          }
        }
      val = (float)(scale * acc);
    }
    coef[off + e] = val;
  }
}

// ---------------------------------------------------------------------------
// Main kernel: one thread per hi-res pixel.
// ---------------------------------------------------------------------------

template<int NA, int NB, int NC, int NCP>
__device__ __forceinline__ void tp_path(const float* cf, const float* xa, const float* yb, float* oc) {
#pragma unroll
  for (int i = 0; i < NA; ++i) {
#pragma unroll
    for (int j = 0; j < NB; ++j) {
      float t = xa[i] * yb[j];
      const float4* run = reinterpret_cast<const float4*>(cf + (i*NB + j)*NCP);
#pragma unroll
      for (int q = 0; q < NCP/4; ++q) {
        float4 c4 = run[q];
        if (4*q+0 < NC) oc[4*q+0] = fmaf(c4.x, t, oc[4*q+0]);
        if (4*q+1 < NC) oc[4*q+1] = fmaf(c4.y, t, oc[4*q+1]);
        if (4*q+2 < NC) oc[4*q+2] = fmaf(c4.z, t, oc[4*q+2]);
        if (4*q+3 < NC) oc[4*q+3] = fmaf(c4.w, t, oc[4*q+3]);
      }
    }
  }
}

__global__ __launch_bounds__(256) void eqconv_main(
    const float* __restrict__ f4, const float* __restrict__ f6,
    const float* __restrict__ sw, const float* __restrict__ coef,
    float* __restrict__ out) {
  __shared__ float sc[CSZ];
  for (int t = threadIdx.x; t < CSZ/4; t += 256)
    reinterpret_cast<float4*>(sc)[t] = reinterpret_cast<const float4*>(coef)[t];
  __syncthreads();

  const int n  = blockIdx.x * 256 + threadIdx.x;
  const int Yh = n >> 9, Xh = n & 511;
  const int ry = Yh >> 2, cx = Xh >> 2;
  // 3x3 conv taps on the 4x-replicated image touch at most 2 distinct low-res
  // rows/cols (edge-clamped).
  const int rm = (Yh == 0)   ? ry : ((Yh - 1) >> 2);
  const int rp = (Yh == 511) ? ry : ((Yh + 1) >> 2);
  const int cm = (Xh == 0)   ? cx : ((Xh - 1) >> 2);
  const int cp = (Xh == 511) ? cx : ((Xh + 1) >> 2);
  const int r2 = (rm != ry) ? rm : ((rp != ry) ? rp : ry);
  const int c2 = (cm != cx) ? cm : ((cp != cx) ? cp : cx);
  const int sR0 = (rm != ry) ? 1 : 0, sR2 = (rp != ry) ? 1 : 0;
  const int sC0 = (cm != cx) ? 1 : 0, sC2 = (cp != cx) ? 1 : 0;

  // collapse the 3x3 kernel onto the (<=2)x(<=2) distinct low-res pixels
  float A00 = 0.f, A01 = 0.f, A10 = 0.f, A11 = 0.f;
#pragma unroll
  for (int dy = 0; dy < 3; ++dy) {
    const int rs = (dy == 0) ? sR0 : ((dy == 2) ? sR2 : 0);
#pragma unroll
    for (int dx = 0; dx < 3; ++dx) {
      const int cs = (dx == 0) ? sC0 : ((dx == 2) ? sC2 : 0);
      const float ww = sw[dy*3 + dx];
      A00 += (rs == 0 && cs == 0) ? ww : 0.f;
      A01 += (rs == 0 && cs != 0) ? ww : 0.f;
      A10 += (rs != 0 && cs == 0) ? ww : 0.f;
      A11 += (rs != 0 && cs != 0) ? ww : 0.f;
    }
  }

  const int o00 = ry*128 + cx, o01 = ry*128 + c2, o10 = r2*128 + cx, o11 = r2*128 + c2;

  float x[22], y[22];
#pragma unroll
  for (int c = 0; c < 9; ++c) {
    float v00 = f4[o00*9 + c], v01 = f4[o01*9 + c];
    float v10 = f4[o10*9 + c], v11 = f4[o11*9 + c];
    x[c] = v00;
    y[c] = A00*v00 + A01*v01 + A10*v10 + A11*v11;
  }
#pragma unroll
  for (int c = 0; c < 13; ++c) {
    float v00 = f6[o00*13 + c], v01 = f6[o01*13 + c];
    float v10 = f6[o10*13 + c], v11 = f6[o11*13 + c];
    x[9 + c] = v00;
    y[9 + c] = A00*v00 + A01*v01 + A10*v10 + A11*v11;
  }

  float o4[9]  = {0.f,0.f,0.f,0.f,0.f,0.f,0.f,0.f,0.f};
  float o6[13] = {0.f,0.f,0.f,0.f,0.f,0.f,0.f,0.f,0.f,0.f,0.f,0.f,0.f};

  // paths in PATHS order; offsets into padded coef table
  tp_path<9, 9, 9, 12>(sc + 0,     x,     y,     o4);   // (4,4,4)
  tp_path<9, 9, 13,16>(sc + 972,   x,     y,     o6);   // (4,4,6)
  tp_path<9, 13,9, 12>(sc + 2268,  x,     y + 9, o4);   // (4,6,4)
  tp_path<9, 13,13,16>(sc + 3672,  x,     y + 9, o6);   // (4,6,6)
  tp_path<13,9, 9, 12>(sc + 5544,  x + 9, y,     o4);   // (6,4,4)
  tp_path<13,9, 13,16>(sc + 6948,  x + 9, y,     o6);   // (6,4,6)
  tp_path<13,13,9, 12>(sc + 8820,  x + 9, y + 9, o4);   // (6,6,4)
  tp_path<13,13,13,16>(sc + 10848, x + 9, y + 9, o6);   // (6,6,6)

#pragma unroll
  for (int k = 0; k < 9; ++k)  out[n*9 + k] = o4[k] + x[k];
#pragma unroll
  for (int k = 0; k < 13; ++k) out[NPIX*9 + n*13 + k] = o6[k] + x[9 + k];
}

extern "C" void kernel_launch(void* const* d_in, const int* in_sizes, int n_in,
                              void* d_out, int out_size, void* d_ws, size_t ws_size,
                              hipStream_t stream) {
  const float* f4  = (const float*)d_in[0];
  const float* f6  = (const float*)d_in[1];
  const float* sw  = (const float*)d_in[2];
  const float* tpw = (const float*)d_in[3];
  float* coef = (float*)d_ws;
  float* out  = (float*)d_out;

  hipLaunchKernelGGL(w3j_init, dim3(8), dim3(256), 0, stream, tpw, coef);
  hipLaunchKernelGGL(eqconv_main, dim3(NPIX/256), dim3(256), 0, stream,
                     f4, f6, sw, coef, out);
}

// Round 2
// 41.792 us; speedup vs baseline: 6.7987x; 6.7987x over previous
//
#include <hip/hip_runtime.h>

#define NPIX (512*512)

// ---------------------------------------------------------------------------
// Init kernel: build the 8 per-path coefficient tensors coef[p][i][j][k] =
// 0.5 * tp_w[p] * Cr[i][j][k]  (Cr = real-basis Wigner 3j * sqrt(2lc+1)),
// padded so each k-run is a multiple of 4 floats (12 for nc=9, 16 for nc=13).
// Table layout (floats): offsets {0,972,2268,3672,5544,6948,8820,10848}, 13552 total.
// ---------------------------------------------------------------------------

static __device__ __forceinline__ int qcol(int l, int c, int* row, double* re, double* im) {
  const double S = 0.70710678118654752440;  // 1/sqrt(2)
  int p = c - l;
  if (p == 0) { row[0] = l; re[0] = 1.0; im[0] = 0.0; return 1; }
  if (p > 0) {
    row[0] = l - p; re[0] = S;                 im[0] = 0.0;
    row[1] = l + p; re[1] = (p & 1) ? -S : S;  im[1] = 0.0;
    return 2;
  }
  int a = -p;
  row[0] = l - a; re[0] = 0.0; im[0] = -S;
  row[1] = l + a; re[1] = 0.0; im[1] = (a & 1) ? -S : S;
  return 2;
}

__global__ void w3j_init(const float* __restrict__ tpw, float* __restrict__ coef) {
  __shared__ double sC[13*13*13];
  __shared__ double sfact[20];
  const int p = blockIdx.x;
  const int la = (p & 4) ? 6 : 4, lb = (p & 2) ? 6 : 4, lc = (p & 1) ? 6 : 4;
  const int na = 2*la+1, nb = 2*lb+1, nc = 2*lc+1, ncp = (nc + 3) & ~3;
  if (threadIdx.x == 0) {
    double f = 1.0; sfact[0] = 1.0;
    for (int i = 1; i < 20; ++i) { f *= (double)i; sfact[i] = f; }
  }
  int off = 0;
  for (int q = 0; q < p; ++q)
    off += ((q&4)?13:9) * ((q&2)?13:9) * ((q&1)?16:12);
  for (int e = threadIdx.x; e < na*nb*nc; e += blockDim.x) sC[e] = 0.0;
  __syncthreads();
  for (int e = threadIdx.x; e < na*nb; e += blockDim.x) {
    int i = e / nb, j = e % nb;
    int m1 = i - la, m2 = j - lb, m3 = m1 + m2;
    if (m3 < -lc || m3 > lc) continue;
    double pre = sqrt((2.0*lc + 1.0) * sfact[lc+la-lb] * sfact[lc-la+lb] * sfact[la+lb-lc] / sfact[la+lb+lc+1]);
    pre *= sqrt(sfact[lc+m3]*sfact[lc-m3]*sfact[la-m1]*sfact[la+m1]*sfact[lb-m2]*sfact[lb+m2]);
    double s = 0.0;
    for (int k = 0; k <= la + lb - lc; ++k) {
      int d2 = la - m1 - k, d3 = lb + m2 - k, d4 = lc - lb + m1 + k, d5 = lc - la - m2 + k;
      if (d2 < 0 || d3 < 0 || d4 < 0 || d5 < 0) continue;
      s += ((k & 1) ? -1.0 : 1.0) /
           (sfact[k]*sfact[la+lb-lc-k]*sfact[d2]*sfact[d3]*sfact[d4]*sfact[d5]);
    }
    sC[(i*nb + j)*nc + (lc + m3)] = pre * s;
  }
  __syncthreads();
  const double PH = (((la/2)&1)?-1.0:1.0)*(((lb/2)&1)?-1.0:1.0)*(((lc/2)&1)?-1.0:1.0);
  const double scale = 0.5 * (double)tpw[p] * PH;
  for (int e = threadIdx.x; e < na*nb*ncp; e += blockDim.x) {
    int a = e / (nb*ncp), rem = e % (nb*ncp), b = rem / ncp, c = rem % ncp;
    float val = 0.0f;
    if (c < nc) {
      int r1[2]; double u1r[2], u1i[2]; int n1 = qcol(la, a, r1, u1r, u1i);
      int r2[2]; double u2r[2], u2i[2]; int n2 = qcol(lb, b, r2, u2r, u2i);
      int r3[2]; double u3r[2], u3i[2]; int n3 = qcol(lc, c, r3, u3r, u3i);
      double acc = 0.0;
      for (int u = 0; u < n1; ++u)
        for (int v = 0; v < n2; ++v) {
          double Rr = u1r[u]*u2r[v] - u1i[u]*u2i[v];
          double Ri = u1r[u]*u2i[v] + u1i[u]*u2r[v];
          for (int w = 0; w < n3; ++w) {
            double cv = sC[(r1[u]*nb + r2[v])*nc + r3[w]];
            acc += (Rr*u3r[w] + Ri*u3i[w]) * cv;
          }
        }
      val = (float)(scale * acc);
    }
    coef[off + e] = val;
  }
}

// ---------------------------------------------------------------------------
// Main kernel.
// Block = 16 consecutive low-res pixels in one row  (256 threads, 1024 blocks).
// Phase 1: M[p][j][k] = sum_la sum_i C[i][j][k] * x[p][i]   (616 floats/pixel,
//          merged over la), each of 154 threads owns one float4 entry for all
//          16 pixels; coef table scanned once per block from global (L2-hot).
// Phase 2: per hi-res pixel: conv -> y[22]; out[k] = sum_j y_j M[j][k] + x.
// M LDS stride = 620 floats so the 4 broadcast groups in a wave hit disjoint banks.
// ---------------------------------------------------------------------------

#define MSTRIDE 620

template<int NJ, int NC, int NCP>
__device__ __forceinline__ void mv_path(const float* mf, const float* yv, float* oc) {
#pragma unroll
  for (int j = 0; j < NJ; ++j) {
    float t = yv[j];
    const float4* run = reinterpret_cast<const float4*>(mf + j*NCP);
#pragma unroll
    for (int q = 0; q < NCP/4; ++q) {
      float4 c4 = run[q];
      if (4*q+0 < NC) oc[4*q+0] = fmaf(c4.x, t, oc[4*q+0]);
      if (4*q+1 < NC) oc[4*q+1] = fmaf(c4.y, t, oc[4*q+1]);
      if (4*q+2 < NC) oc[4*q+2] = fmaf(c4.z, t, oc[4*q+2]);
      if (4*q+3 < NC) oc[4*q+3] = fmaf(c4.w, t, oc[4*q+3]);
    }
  }
}

__global__ __launch_bounds__(256) void eqconv_main(
    const float* __restrict__ f4, const float* __restrict__ f6,
    const float* __restrict__ sw, const float* __restrict__ coef,
    float* __restrict__ out) {
  __shared__ float M_lds[16 * MSTRIDE];
  __shared__ float xT[22][16];

  const int tid = threadIdx.x;
  const int ry  = blockIdx.x >> 3;
  const int cx0 = (blockIdx.x & 7) * 16;

  // ---- stage x (transposed) ----
  for (int t = tid; t < 352; t += 256) {
    int p = t / 22, c = t % 22;
    int pix = (ry * 128 + cx0 + p);
    float v = (c < 9) ? f4[pix*9 + c] : f6[pix*13 + (c - 9)];
    xT[c][p] = v;
  }
  __syncthreads();

  // ---- phase 1: build M ----
  const int q = tid;
  if (q < 154) {
    // entry -> (class, j, kq)
    int cls, jj, kq;
    if (q < 27)       { cls = 0; jj = q / 3;          kq = q % 3; }
    else if (q < 63)  { cls = 1; jj = (q - 27) / 4;   kq = (q - 27) % 4; }
    else if (q < 102) { cls = 2; jj = (q - 63) / 3;   kq = (q - 63) % 3; }
    else              { cls = 3; jj = (q - 102) / 4;  kq = (q - 102) % 4; }
    // class tables: (lb,lc) = (4,4),(4,6),(6,4),(6,6)
    const int ncp  = (cls == 0 || cls == 2) ? 12 : 16;
    const int str  = (cls == 0) ? 108 : (cls == 1) ? 144 : (cls == 2) ? 156 : 208; // (2lb+1)*ncp
    const int off4 = (cls == 0) ? 0   : (cls == 1) ? 972 : (cls == 2) ? 2268 : 3672;
    const int off6 = (cls == 0) ? 5544: (cls == 1) ? 6948: (cls == 2) ? 8820 : 10848;
    const int base4 = off4 + jj*ncp + 4*kq;
    const int base6 = off6 + jj*ncp + 4*kq;

    float4 acc[16];
#pragma unroll
    for (int p = 0; p < 16; ++p) acc[p] = make_float4(0.f, 0.f, 0.f, 0.f);

    // la = 4 contribution (i over 9 x4 components)
    for (int i = 0; i < 9; ++i) {
      float4 c4 = *reinterpret_cast<const float4*>(coef + base4 + i*str);
      float xv[16];
      *reinterpret_cast<float4*>(&xv[0])  = *reinterpret_cast<const float4*>(&xT[i][0]);
      *reinterpret_cast<float4*>(&xv[4])  = *reinterpret_cast<const float4*>(&xT[i][4]);
      *reinterpret_cast<float4*>(&xv[8])  = *reinterpret_cast<const float4*>(&xT[i][8]);
      *reinterpret_cast<float4*>(&xv[12]) = *reinterpret_cast<const float4*>(&xT[i][12]);
#pragma unroll
      for (int p = 0; p < 16; ++p) {
        acc[p].x = fmaf(c4.x, xv[p], acc[p].x);
        acc[p].y = fmaf(c4.y, xv[p], acc[p].y);
        acc[p].z = fmaf(c4.z, xv[p], acc[p].z);
        acc[p].w = fmaf(c4.w, xv[p], acc[p].w);
      }
    }
    // la = 6 contribution (i over 13 x6 components)
    for (int i = 0; i < 13; ++i) {
      float4 c4 = *reinterpret_cast<const float4*>(coef + base6 + i*str);
      float xv[16];
      *reinterpret_cast<float4*>(&xv[0])  = *reinterpret_cast<const float4*>(&xT[9+i][0]);
      *reinterpret_cast<float4*>(&xv[4])  = *reinterpret_cast<const float4*>(&xT[9+i][4]);
      *reinterpret_cast<float4*>(&xv[8])  = *reinterpret_cast<const float4*>(&xT[9+i][8]);
      *reinterpret_cast<float4*>(&xv[12]) = *reinterpret_cast<const float4*>(&xT[9+i][12]);
#pragma unroll
      for (int p = 0; p < 16; ++p) {
        acc[p].x = fmaf(c4.x, xv[p], acc[p].x);
        acc[p].y = fmaf(c4.y, xv[p], acc[p].y);
        acc[p].z = fmaf(c4.z, xv[p], acc[p].z);
        acc[p].w = fmaf(c4.w, xv[p], acc[p].w);
      }
    }
#pragma unroll
    for (int p = 0; p < 16; ++p)
      *reinterpret_cast<float4*>(&M_lds[p*MSTRIDE + 4*q]) = acc[p];
  }
  __syncthreads();

  // ---- phase 2: per hi-res pixel ----
  const int p  = tid >> 4;
  const int w  = tid & 15;
  const int dy = w >> 2, dx = w & 3;
  const int cx = cx0 + p;
  const int Yh = ry*4 + dy, Xh = cx*4 + dx;

  const int rm = (Yh == 0)   ? ry : ((Yh - 1) >> 2);
  const int rp = (Yh == 511) ? ry : ((Yh + 1) >> 2);
  const int cm = (Xh == 0)   ? cx : ((Xh - 1) >> 2);
  const int cp = (Xh == 511) ? cx : ((Xh + 1) >> 2);
  const int r2 = (rm != ry) ? rm : ((rp != ry) ? rp : ry);
  const int c2 = (cm != cx) ? cm : ((cp != cx) ? cp : cx);
  const int sR0 = (rm != ry) ? 1 : 0, sR2 = (rp != ry) ? 1 : 0;
  const int sC0 = (cm != cx) ? 1 : 0, sC2 = (cp != cx) ? 1 : 0;

  float A00 = 0.f, A01 = 0.f, A10 = 0.f, A11 = 0.f;
#pragma unroll
  for (int ddy = 0; ddy < 3; ++ddy) {
    const int rs = (ddy == 0) ? sR0 : ((ddy == 2) ? sR2 : 0);
#pragma unroll
    for (int ddx = 0; ddx < 3; ++ddx) {
      const int cs = (ddx == 0) ? sC0 : ((ddx == 2) ? sC2 : 0);
      const float ww = sw[ddy*3 + ddx];
      A00 += (rs == 0 && cs == 0) ? ww : 0.f;
      A01 += (rs == 0 && cs != 0) ? ww : 0.f;
      A10 += (rs != 0 && cs == 0) ? ww : 0.f;
      A11 += (rs != 0 && cs != 0) ? ww : 0.f;
    }
  }

  const int o01 = ry*128 + c2, o10 = r2*128 + cx, o11 = r2*128 + c2;

  float y[22];
#pragma unroll
  for (int c = 0; c < 9; ++c) {
    float v00 = xT[c][p];
    float v01 = f4[o01*9 + c], v10 = f4[o10*9 + c], v11 = f4[o11*9 + c];
    y[c] = A00*v00 + A01*v01 + A10*v10 + A11*v11;
  }
#pragma unroll
  for (int c = 0; c < 13; ++c) {
    float v00 = xT[9 + c][p];
    float v01 = f6[o01*13 + c], v10 = f6[o10*13 + c], v11 = f6[o11*13 + c];
    y[9 + c] = A00*v00 + A01*v01 + A10*v10 + A11*v11;
  }

  float o4[9]  = {0.f,0.f,0.f,0.f,0.f,0.f,0.f,0.f,0.f};
  float o6[13] = {0.f,0.f,0.f,0.f,0.f,0.f,0.f,0.f,0.f,0.f,0.f,0.f,0.f};

  const float* Mb = &M_lds[p * MSTRIDE];
  mv_path<9, 9, 12>(Mb + 0,   y,     o4);   // (lb=4 -> lc=4), floats [0,108)
  mv_path<9, 13,16>(Mb + 108, y,     o6);   // (lb=4 -> lc=6), [108,252)
  mv_path<13,9, 12>(Mb + 252, y + 9, o4);   // (lb=6 -> lc=4), [252,408)
  mv_path<13,13,16>(Mb + 408, y + 9, o6);   // (lb=6 -> lc=6), [408,616)

  const int n = Yh*512 + Xh;
#pragma unroll
  for (int k = 0; k < 9; ++k)  out[n*9 + k] = o4[k] + xT[k][p];
#pragma unroll
  for (int k = 0; k < 13; ++k) out[NPIX*9 + n*13 + k] = o6[k] + xT[9 + k][p];
}

extern "C" void kernel_launch(void* const* d_in, const int* in_sizes, int n_in,
                              void* d_out, int out_size, void* d_ws, size_t ws_size,
                              hipStream_t stream) {
  const float* f4  = (const float*)d_in[0];
  const float* f6  = (const float*)d_in[1];
  const float* sw  = (const float*)d_in[2];
  const float* tpw = (const float*)d_in[3];
  float* coef = (float*)d_ws;
  float* out  = (float*)d_out;

  hipLaunchKernelGGL(w3j_init, dim3(8), dim3(256), 0, stream, tpw, coef);
  hipLaunchKernelGGL(eqconv_main, dim3(1024), dim3(256), 0, stream,
                     f4, f6, sw, coef, out);
}